// Round 8
// baseline (125.178 us; speedup 1.0000x reference)
//
#include <hip/hip_runtime.h>
#include <math.h>

#define BATCH 256
#define DIN 784
#define DH 512
#define DOUT 10
#define SPLITS 56
#define KSPL 14  // 784 / 56

// Fast softplus: w_sigma* inputs are uniform[-12,-2]; native v_exp/v_log give
// ~1e-7 rel error -- output threshold is ~2% relative. Verified absmax 1.9e-6.
__device__ __forceinline__ float softplus(float x) {
  return __logf(1.0f + __expf(x));
}

// ---------------------------------------------------------------------------
// Kernel 1: layer-1 dual GEMM, k-split. Grid (8 hTiles, 2 bTiles, 56 splits)
// = 896 blocks (3.5/CU, 14 waves/CU; LDS ~14.6 KB). Block tile: 64 h x 128 b,
// k-chunk 14. Thread: 4 h x 8 b (k-pair unroll) -> per k-pair: 4 ds_read_b128
// (weights) + 8 ds_read_b64 (x) = 96 LDS-cyc for 128 FMAs (1.0 B/FMA, down
// from 1.5 -- the LDS pipe is byte-bound at ~85 B/cyc/CU and was the limiter).
//   mu_part[s][b][h] = sum_k x[b,k] * w_mu1[k,h]
//   q_part [s][b][h] = sum_k x[b,k]^2 * softplus(w_sigma1[h,k])
// KL partials (no atomics, no init): 912 slots in kl_part
//   y==0: sum (sp - log sp) over wst tile (LDS)       -> slot x*56+s  [0,448)
//   y==1: sum w_mu1^2 over wmt tile (LDS)             -> slot 448+x*56+s
//   y==0,x==0,s<16: sp(ws2)-log sp(ws2)+w_mu2^2 slice -> slot 896+s (2nd red)
// ---------------------------------------------------------------------------
__global__ __launch_bounds__(256) void gemm1_kernel(
    const float* __restrict__ x, const float* __restrict__ w_mu1,
    const float* __restrict__ w_sigma1, const float* __restrict__ w_mu2,
    const float* __restrict__ w_sigma2, float* __restrict__ mu_part,
    float* __restrict__ q_part, float* __restrict__ kl_part) {
  __shared__ float xs[128][KSPL];  // [b][k], 56B rows (8B-aligned pairs)
  __shared__ float wmt[KSPL][68];  // [k][h], h padded 64->68 (16B-aligned)
  __shared__ float wst[KSPL][68];
  __shared__ float rlds[4];
  const int t = threadIdx.x;
  const int h0 = blockIdx.x * 64;
  const int b0 = blockIdx.y * 128;
  const int s = blockIdx.z;
  const int i0 = s * KSPL;
  const int hl = (t & 15) * 4;  // 16 h-groups of 4
  const int bg = (t >> 4) * 8;  // 16 b-groups of 8

  // stage x rows (128 x 14, 56B runs)
  for (int f = t; f < 128 * KSPL; f += 256) {
    const int bb = f / KSPL, kk = f - bb * KSPL;
    xs[bb][kk] = x[(b0 + bb) * DIN + i0 + kk];
  }
  // stage w_mu1 tile (14 x 64, coalesced 64-rows)
  for (int f = t; f < KSPL * 64; f += 256) {
    const int kk = f >> 6, hh = f & 63;
    wmt[kk][hh] = w_mu1[(i0 + kk) * DH + h0 + hh];
  }
  // stage softplus(w_sigma1) tile, transposed to [k][h]
  for (int f = t; f < 64 * KSPL; f += 256) {
    const int hh = f / KSPL, kk = f - hh * KSPL;
    wst[kk][hh] = softplus(w_sigma1[(h0 + hh) * DIN + i0 + kk]);
  }
  __syncthreads();

  float mu[8][4], qq[8][4];
#pragma unroll
  for (int j = 0; j < 8; j++)
#pragma unroll
    for (int i = 0; i < 4; i++) {
      mu[j][i] = 0.f;
      qq[j][i] = 0.f;
    }

#pragma unroll
  for (int kk = 0; kk < KSPL; kk += 2) {
    const float4 wm0 = *(const float4*)&wmt[kk][hl];
    const float4 wm1 = *(const float4*)&wmt[kk + 1][hl];
    const float4 ws0 = *(const float4*)&wst[kk][hl];
    const float4 ws1 = *(const float4*)&wst[kk + 1][hl];
    const float* wm0a = (const float*)&wm0;
    const float* wm1a = (const float*)&wm1;
    const float* ws0a = (const float*)&ws0;
    const float* ws1a = (const float*)&ws1;
#pragma unroll
    for (int j = 0; j < 8; j++) {
      const float2 xv = *(const float2*)&xs[bg + j][kk];
      const float xx = xv.x, xy = xv.y;
      const float x2 = xx * xx, y2 = xy * xy;
#pragma unroll
      for (int i = 0; i < 4; i++) {
        mu[j][i] = fmaf(wm0a[i], xx, mu[j][i]);
        mu[j][i] = fmaf(wm1a[i], xy, mu[j][i]);
        qq[j][i] = fmaf(ws0a[i], x2, qq[j][i]);
        qq[j][i] = fmaf(ws1a[i], y2, qq[j][i]);
      }
    }
  }

  const int h = h0 + hl;
  const size_t base = (size_t)s * (BATCH * DH);
#pragma unroll
  for (int j = 0; j < 8; j++) {
    const size_t row = base + (size_t)(b0 + bg + j) * DH + h;
    *(float4*)&mu_part[row] =
        make_float4(mu[j][0], mu[j][1], mu[j][2], mu[j][3]);
    *(float4*)&q_part[row] =
        make_float4(qq[j][0], qq[j][1], qq[j][2], qq[j][3]);
  }

  // ---- fused KL partials (tile scans hit LDS, not global) ----
  const int lane = t & 63, wv = t >> 6;
  float kl = 0.f;
  int slot = -1;
  if (blockIdx.y == 0) {
    for (int f = t; f < KSPL * 64; f += 256) {
      const int kk = f >> 6, hh = f & 63;
      const float sv = wst[kk][hh];
      kl += sv - __logf(sv);
    }
    slot = blockIdx.x * 56 + s;
  } else {
    for (int f = t; f < KSPL * 64; f += 256) {
      const int kk = f >> 6, hh = f & 63;
      const float wv2 = wmt[kk][hh];
      kl = fmaf(wv2, wv2, kl);
    }
    slot = 448 + blockIdx.x * 56 + s;
  }
  for (int off = 32; off > 0; off >>= 1) kl += __shfl_down(kl, off);
  if (lane == 0) rlds[wv] = kl;
  __syncthreads();
  if (t == 0) kl_part[slot] = rlds[0] + rlds[1] + rlds[2] + rlds[3];

  // layer-2 weights' KL slice (16 blocks do a second reduction)
  if (blockIdx.y == 0 && blockIdx.x == 0 && s < 16) {
    float kl2 = 0.f;
    for (int idx = s * 320 + t; idx < s * 320 + 320; idx += 256) {
      const float sv = softplus(w_sigma2[idx]);
      const float wv2 = w_mu2[idx];
      kl2 += sv - __logf(sv);
      kl2 = fmaf(wv2, wv2, kl2);
    }
    for (int off = 32; off > 0; off >>= 1) kl2 += __shfl_down(kl2, off);
    __syncthreads();
    if (lane == 0) rlds[wv] = kl2;
    __syncthreads();
    if (t == 0) kl_part[896 + s] = rlds[0] + rlds[1] + rlds[2] + rlds[3];
  }
}

// ---------------------------------------------------------------------------
// Kernel 2: fused layer-1 epilogue + layer-2 + softmax + Jacobian sandwich +
// KL finalize. One block of 512 threads per batch row (8 waves/CU). Split
// reduction: thread halves each sum 28 splits of one float4; trace recompute
// parallelized over 70 threads (10 o x 7 split-groups of 8).
// ---------------------------------------------------------------------------
__global__ __launch_bounds__(512) void layer2_kernel(
    const float* __restrict__ mu_part, const float* __restrict__ q_part,
    const float* __restrict__ b_mu1, const float* __restrict__ b_sigma1,
    const float* __restrict__ w_mu2, const float* __restrict__ w_sigma2,
    const float* __restrict__ b_mu2, const float* __restrict__ b_sigma2,
    const float* __restrict__ kl_part, float* __restrict__ out_p,
    float* __restrict__ out_sigma, float* __restrict__ out_kl) {
  const int b = blockIdx.x, t = threadIdx.x;
  __shared__ float smuA[DH], sqA[DH], smuB[DH], sqB[DH];
  __shared__ float4 trp[10][7];
  __shared__ float red[8][75];
  __shared__ float fin[75];
  __shared__ float mu3[10], pvec[10], trv[10], spb2[10];
  __shared__ float sig[10][10], Tm[10][10], cs[10], rs[10];
  __shared__ float klred[8];

  // vectorized split reduction: 512 threads = 2 halves x 2 arrays x 128 quads
  {
    const int half = t >> 8;       // 0: splits 0..27, 1: splits 28..55
    const int arr = (t >> 7) & 1;  // 0: mu, 1: q
    const int h4 = (t & 127) * 4;
    const float* srcbase = (arr == 0 ? mu_part : q_part);
    const float4* src = (const float4*)(srcbase + (size_t)b * DH + h4);
    float4 a = make_float4(0.f, 0.f, 0.f, 0.f);
#pragma unroll
    for (int s2 = half * 28; s2 < half * 28 + 28; s2++) {
      const float4 v = src[(size_t)s2 * (BATCH * DH / 4)];
      a.x += v.x;
      a.y += v.y;
      a.z += v.z;
      a.w += v.w;
    }
    float* dst =
        (half == 0 ? (arr == 0 ? smuA : sqA) : (arr == 0 ? smuB : sqB));
    *(float4*)&dst[h4] = a;
  }

  // trace recompute partials: t<70 -> (o = t/7, g = t%7) sums 8 splits
  if (t < 70) {
    const int o = t / 7, g = t % 7;
    const int cc = (b * 10 + o) & 255;
    float mua = 0.f, qa = 0.f, mub = 0.f, qb = 0.f;
#pragma unroll
    for (int s2 = 8 * g; s2 < 8 * g + 8; s2++) {
      const size_t base = (size_t)s2 * (BATCH * DH) + (size_t)cc * DH;
      mua += mu_part[base + cc];
      qa += q_part[base + cc];
      mub += mu_part[base + 256 + cc];
      qb += q_part[base + 256 + cc];
    }
    trp[o][g] = make_float4(mua, qa, mub, qb);
  }
  __syncthreads();

  const int h = t;  // one h per thread
  float m2h, d2h;
  {
    const float ma = smuA[h] + smuB[h] + b_mu1[h];
    m2h = ma > 0.f ? ma : 0.f;
    d2h = ma > 0.f ? (sqA[h] + sqB[h] + softplus(b_sigma1[h])) : 0.f;
  }

  float acc[75];
#pragma unroll
  for (int i = 0; i < 75; i++) acc[i] = 0.f;
  {
    const float msq = m2h * m2h;
    float wrow[10];
#pragma unroll
    for (int o = 0; o < 10; o++) wrow[o] = w_mu2[h * 10 + o];
#pragma unroll
    for (int o = 0; o < 10; o++) {
      acc[o] = fmaf(wrow[o], m2h, acc[o]);
      acc[10 + o] = fmaf(softplus(w_sigma2[o * DH + h]), msq, acc[10 + o]);
    }
    int idx = 20;
#pragma unroll
    for (int o = 0; o < 10; o++) {
      const float wd = wrow[o] * d2h;
#pragma unroll
      for (int p = o; p < 10; p++) {
        acc[idx] = fmaf(wd, wrow[p], acc[idx]);
        idx++;
      }
    }
  }

  const int lane = t & 63, wv = t >> 6;
#pragma unroll
  for (int j = 0; j < 75; j++) {
    float v = acc[j];
    for (int off = 32; off > 0; off >>= 1) v += __shfl_down(v, off);
    if (lane == 0) red[wv][j] = v;
  }
  __syncthreads();
  if (t < 75) {
    float v = 0.f;
#pragma unroll
    for (int w = 0; w < 8; w++) v += red[w][t];
    fin[t] = v;
  }
  __syncthreads();

  if (t < 10) {
    mu3[t] = fin[t] + b_mu2[t];
    spb2[t] = softplus(b_sigma2[t]);
    // faithful replication of the reshape-trace: tr[b,o] = tr_raw[o2, c]
    const int c0 = b * 10 + t;
    const int o2 = c0 >> 8, cc = c0 & 255;
    float mua = b_mu1[cc], qa = 0.f;
    float mub = b_mu1[256 + cc], qb = 0.f;
#pragma unroll
    for (int g = 0; g < 7; g++) {
      const float4 v = trp[t][g];
      mua += v.x;
      qa += v.y;
      mub += v.z;
      qb += v.w;
    }
    const float d2aa = mua > 0.f ? (qa + softplus(b_sigma1[cc])) : 0.f;
    const float d2bb = mub > 0.f ? (qb + softplus(b_sigma1[256 + cc])) : 0.f;
    trv[t] = softplus(w_sigma2[o2 * DH + 2 * cc]) * d2aa +
             softplus(w_sigma2[o2 * DH + 2 * cc + 1]) * d2bb;
  }
  __syncthreads();

  if (t == 0) {
    float mx = mu3[0];
#pragma unroll
    for (int o = 1; o < 10; o++) mx = fmaxf(mx, mu3[o]);
    float e[10], se = 0.f;
#pragma unroll
    for (int o = 0; o < 10; o++) {
      e[o] = __expf(mu3[o] - mx);
      se += e[o];
    }
    const float inv = 1.f / se;
#pragma unroll
    for (int o = 0; o < 10; o++) pvec[o] = e[o] * inv;
  }
  __syncthreads();

  if (t < 100) {
    const int o = t / 10, p = t % 10;
    const int i0 = o < p ? o : p, j0 = o < p ? p : o;
    const int idx = 10 * i0 - (i0 * (i0 - 1)) / 2 + (j0 - i0);
    float v = fin[20 + idx];  // mid[o][p]
    if (o == p) v += trv[o] + fin[10 + o] + spb2[o];
    sig[o][p] = v;
  }
  __syncthreads();

  if (t < 10) {  // cs[k] = sum_j p[j] * sig[j][k]
    float s = 0.f;
#pragma unroll
    for (int j = 0; j < 10; j++) s = fmaf(pvec[j], sig[j][t], s);
    cs[t] = s;
  }
  __syncthreads();

  if (t < 100) {  // T[i][k] = p[i] * (sig[i][k] - cs[k])
    const int o = t / 10, p = t % 10;
    Tm[o][p] = pvec[o] * (sig[o][p] - cs[p]);
  }
  __syncthreads();

  if (t < 10) {  // rs[i] = sum_k T[i][k] * p[k]
    float s = 0.f;
#pragma unroll
    for (int k = 0; k < 10; k++) s = fmaf(Tm[t][k], pvec[k], s);
    rs[t] = s;
  }
  __syncthreads();

  if (t < 100) {  // Sigma_out[i][l] = p[l] * (T[i][l] - rs[i])
    const int o = t / 10, p = t % 10;
    out_sigma[b * 100 + t] = pvec[p] * (Tm[o][p] - rs[o]);
  }
  if (t < 10) out_p[b * 10 + t] = pvec[t];

  // ---- KL finalize (block 0 only; sync executed uniformly by all) ----
  float klv = 0.f;
  if (b == 0) {
    klv = kl_part[t];
    if (t < 400) klv += kl_part[512 + t];
  }
  for (int off = 32; off > 0; off >>= 1) klv += __shfl_down(klv, off);
  if (lane == 0) klred[wv] = klv;
  __syncthreads();
  if (b == 0 && t == 0) {
    float s = 0.f;
#pragma unroll
    for (int w = 0; w < 8; w++) s += klred[w];
    out_kl[0] = 0.5f * (s - 406528.0f);
  }
}

extern "C" void kernel_launch(void* const* d_in, const int* in_sizes, int n_in,
                              void* d_out, int out_size, void* d_ws,
                              size_t ws_size, hipStream_t stream) {
  const float* x = (const float*)d_in[0];
  const float* w_mu1 = (const float*)d_in[1];
  const float* w_sigma1 = (const float*)d_in[2];
  const float* b_mu1 = (const float*)d_in[3];
  const float* b_sigma1 = (const float*)d_in[4];
  const float* w_mu2 = (const float*)d_in[5];
  const float* w_sigma2 = (const float*)d_in[6];
  const float* b_mu2 = (const float*)d_in[7];
  const float* b_sigma2 = (const float*)d_in[8];

  float* out = (float*)d_out;
  float* out_p = out;             // 256*10
  float* out_sigma = out + 2560;  // 256*100
  float* out_kl = out + 28160;    // 1

  float* ws = (float*)d_ws;
  float* mu_part = ws;                            // 56*256*512
  float* q_part = ws + SPLITS * BATCH * DH;       // 56*256*512
  float* kl_part = ws + 2 * SPLITS * BATCH * DH;  // 912

  gemm1_kernel<<<dim3(8, 2, SPLITS), 256, 0, stream>>>(
      x, w_mu1, w_sigma1, w_mu2, w_sigma2, mu_part, q_part, kl_part);
  layer2_kernel<<<256, 512, 0, stream>>>(mu_part, q_part, b_mu1, b_sigma1,
                                         w_mu2, w_sigma2, b_mu2, b_sigma2,
                                         kl_part, out_p, out_sigma, out_kl);
}

// Round 9
// 117.485 us; speedup vs baseline: 1.0655x; 1.0655x over previous
//
#include <hip/hip_runtime.h>
#include <math.h>

#define BATCH 256
#define DIN 784
#define DH 512
#define DOUT 10
#define SPLITS 28
#define KSPL 28  // 784 / 28, even -> no k-pad needed

// Fast softplus: w_sigma* inputs are uniform[-12,-2]; native v_exp/v_log give
// ~1e-7 rel error -- output threshold is ~2% relative. Verified absmax 1.9e-6.
__device__ __forceinline__ float softplus(float x) {
  return __logf(1.0f + __expf(x));
}

// ---------------------------------------------------------------------------
// Kernel 1: layer-1 dual GEMM, k-split. Grid (8 hTiles, 4 bTiles, 28 splits)
// = 896 blocks (~3.5/CU, 14 waves/CU; LDS 22.5 KB/block). Block tile:
// 64 h x 64 b, k-chunk 28. Thread: 4 h x 4 b, k-pair unroll.
// NOTE (round-8 lesson): SPLITS=56 / 128-b tiles double the partial-buffer
// round trip (58.7 MB, cross-XCD -> L3/HBM speed) and cost +9 us net; this
// SPLITS=28 config is the measured optimum of {LDS-issue, occupancy,
// partial-traffic}.
//   mu_part[s][b][h] = sum_k x[b,k] * w_mu1[k,h]
//   q_part [s][b][h] = sum_k x[b,k]^2 * softplus(w_sigma1[h,k])
// KL partials (no atomics, no init): 464 slots in kl_part
//   y==0: sum (sp - log sp) over wst tile (LDS)       -> slot x*28+s
//   y==1: sum w_mu1^2 over wmt tile (LDS)             -> slot 224+x*28+s
//   y==2,x==0,s<16: sp(ws2)-log sp(ws2)+w_mu2^2 slice -> slot 448+s
// ---------------------------------------------------------------------------
__global__ __launch_bounds__(256) void gemm1_kernel(
    const float* __restrict__ x, const float* __restrict__ w_mu1,
    const float* __restrict__ w_sigma1, const float* __restrict__ w_mu2,
    const float* __restrict__ w_sigma2, float* __restrict__ mu_part,
    float* __restrict__ q_part, float* __restrict__ kl_part) {
  __shared__ float xs[64][KSPL];    // [b][k], 112B rows (8B-aligned pairs)
  __shared__ float wmt[KSPL][68];   // [k][h], h padded 64->68 (b128 aligned)
  __shared__ float wst[KSPL][68];
  __shared__ float rlds[4];
  const int t = threadIdx.x;
  const int h0 = blockIdx.x * 64;
  const int b0 = blockIdx.y * 64;
  const int s = blockIdx.z;
  const int i0 = s * KSPL;
  const int hl = (t & 15) * 4;  // 16 h-groups of 4
  const int bg = (t >> 4) * 4;  // 16 b-groups of 4

  // stage x rows (64 x 28, coalesced 28-chunks)
  for (int f = t; f < 64 * KSPL; f += 256) {
    const int bb = f / KSPL, kk = f - bb * KSPL;
    xs[bb][kk] = x[(b0 + bb) * DIN + i0 + kk];
  }
  // stage w_mu1 tile (28 x 64, coalesced 64-rows)
  for (int f = t; f < KSPL * 64; f += 256) {
    const int kk = f >> 6, hh = f & 63;
    wmt[kk][hh] = w_mu1[(i0 + kk) * DH + h0 + hh];
  }
  // stage softplus(w_sigma1) tile, transposed to [k][h]
  for (int f = t; f < 64 * KSPL; f += 256) {
    const int hh = f / KSPL, kk = f - hh * KSPL;
    wst[kk][hh] = softplus(w_sigma1[(h0 + hh) * DIN + i0 + kk]);
  }
  __syncthreads();

  float mu[4][4], qq[4][4];
#pragma unroll
  for (int j = 0; j < 4; j++)
#pragma unroll
    for (int i = 0; i < 4; i++) {
      mu[j][i] = 0.f;
      qq[j][i] = 0.f;
    }

#pragma unroll 7
  for (int kk = 0; kk < KSPL; kk += 2) {
    const float4 wm0 = *(const float4*)&wmt[kk][hl];
    const float4 wm1 = *(const float4*)&wmt[kk + 1][hl];
    const float4 ws0 = *(const float4*)&wst[kk][hl];
    const float4 ws1 = *(const float4*)&wst[kk + 1][hl];
    const float* wm0a = (const float*)&wm0;
    const float* wm1a = (const float*)&wm1;
    const float* ws0a = (const float*)&ws0;
    const float* ws1a = (const float*)&ws1;
#pragma unroll
    for (int j = 0; j < 4; j++) {
      const float2 xv = *(const float2*)&xs[bg + j][kk];
      const float xx = xv.x, xy = xv.y;
      const float x2 = xx * xx, y2 = xy * xy;
#pragma unroll
      for (int i = 0; i < 4; i++) {
        mu[j][i] = fmaf(wm0a[i], xx, mu[j][i]);
        mu[j][i] = fmaf(wm1a[i], xy, mu[j][i]);
        qq[j][i] = fmaf(ws0a[i], x2, qq[j][i]);
        qq[j][i] = fmaf(ws1a[i], y2, qq[j][i]);
      }
    }
  }

  const int h = h0 + hl;
  const size_t base = (size_t)s * (BATCH * DH);
#pragma unroll
  for (int j = 0; j < 4; j++) {
    const size_t row = base + (size_t)(b0 + bg + j) * DH + h;
    *(float4*)&mu_part[row] =
        make_float4(mu[j][0], mu[j][1], mu[j][2], mu[j][3]);
    *(float4*)&q_part[row] =
        make_float4(qq[j][0], qq[j][1], qq[j][2], qq[j][3]);
  }

  // ---- fused KL partials (tile scans hit LDS, not global) ----
  float kl = 0.f;
  int slot = -1;
  if (blockIdx.y == 0) {
    for (int f = t; f < KSPL * 64; f += 256) {
      const int kk = f >> 6, hh = f & 63;
      const float sv = wst[kk][hh];
      kl += sv - __logf(sv);
    }
    slot = blockIdx.x * 28 + s;
  } else if (blockIdx.y == 1) {
    for (int f = t; f < KSPL * 64; f += 256) {
      const int kk = f >> 6, hh = f & 63;
      const float wv = wmt[kk][hh];
      kl = fmaf(wv, wv, kl);
    }
    slot = 224 + blockIdx.x * 28 + s;
  } else if (blockIdx.y == 2 && blockIdx.x == 0 && s < 16) {
    for (int idx = s * 320 + t; idx < s * 320 + 320; idx += 256) {
      const float sv = softplus(w_sigma2[idx]);
      const float wv = w_mu2[idx];
      kl += sv - __logf(sv);
      kl = fmaf(wv, wv, kl);
    }
    slot = 448 + s;
  }

  for (int off = 32; off > 0; off >>= 1) kl += __shfl_down(kl, off);
  const int lane = t & 63, wv = t >> 6;
  if (lane == 0) rlds[wv] = kl;
  __syncthreads();
  if (t == 0 && slot >= 0)
    kl_part[slot] = rlds[0] + rlds[1] + rlds[2] + rlds[3];
}

// ---------------------------------------------------------------------------
// Kernel 2: fused layer-1 epilogue + layer-2 + softmax + Jacobian sandwich +
// KL finalize. One block of 512 threads per batch row (8 waves/CU). Split
// reduction: thread halves each sum 14 splits of one float4; trace recompute
// parallelized over 70 threads (10 o x 7 split-groups of 4).
// ---------------------------------------------------------------------------
__global__ __launch_bounds__(512) void layer2_kernel(
    const float* __restrict__ mu_part, const float* __restrict__ q_part,
    const float* __restrict__ b_mu1, const float* __restrict__ b_sigma1,
    const float* __restrict__ w_mu2, const float* __restrict__ w_sigma2,
    const float* __restrict__ b_mu2, const float* __restrict__ b_sigma2,
    const float* __restrict__ kl_part, float* __restrict__ out_p,
    float* __restrict__ out_sigma, float* __restrict__ out_kl) {
  const int b = blockIdx.x, t = threadIdx.x;
  __shared__ float smuA[DH], sqA[DH], smuB[DH], sqB[DH];
  __shared__ float4 trp[10][7];
  __shared__ float red[8][75];
  __shared__ float fin[75];
  __shared__ float mu3[10], pvec[10], trv[10], spb2[10];
  __shared__ float sig[10][10], Tm[10][10], cs[10], rs[10];
  __shared__ float klred[8];

  // vectorized split reduction: 512 threads = 2 halves x 2 arrays x 128 quads
  {
    const int half = t >> 8;         // 0: splits 0..13, 1: splits 14..27
    const int arr = (t >> 7) & 1;    // 0: mu, 1: q
    const int h4 = (t & 127) * 4;
    const float* srcbase = (arr == 0 ? mu_part : q_part);
    const float4* src = (const float4*)(srcbase + (size_t)b * DH + h4);
    float4 a = make_float4(0.f, 0.f, 0.f, 0.f);
#pragma unroll
    for (int s2 = half * 14; s2 < half * 14 + 14; s2++) {
      const float4 v = src[(size_t)s2 * (BATCH * DH / 4)];
      a.x += v.x;
      a.y += v.y;
      a.z += v.z;
      a.w += v.w;
    }
    float* dst = (half == 0 ? (arr == 0 ? smuA : sqA)
                            : (arr == 0 ? smuB : sqB));
    *(float4*)&dst[h4] = a;
  }

  // trace recompute partials: t<70 -> (o = t/7, g = t%7) sums 4 splits
  if (t < 70) {
    const int o = t / 7, g = t % 7;
    const int cc = (b * 10 + o) & 255;
    float mua = 0.f, qa = 0.f, mub = 0.f, qb = 0.f;
#pragma unroll
    for (int s2 = 4 * g; s2 < 4 * g + 4; s2++) {
      const size_t base = (size_t)s2 * (BATCH * DH) + (size_t)cc * DH;
      mua += mu_part[base + cc];
      qa += q_part[base + cc];
      mub += mu_part[base + 256 + cc];
      qb += q_part[base + 256 + cc];
    }
    trp[o][g] = make_float4(mua, qa, mub, qb);
  }
  __syncthreads();

  const int h = t;  // one h per thread
  float m2h, d2h;
  {
    const float ma = smuA[h] + smuB[h] + b_mu1[h];
    m2h = ma > 0.f ? ma : 0.f;
    d2h = ma > 0.f ? (sqA[h] + sqB[h] + softplus(b_sigma1[h])) : 0.f;
  }

  float acc[75];
#pragma unroll
  for (int i = 0; i < 75; i++) acc[i] = 0.f;
  {
    const float msq = m2h * m2h;
    float wrow[10];
#pragma unroll
    for (int o = 0; o < 10; o++) wrow[o] = w_mu2[h * 10 + o];
#pragma unroll
    for (int o = 0; o < 10; o++) {
      acc[o] = fmaf(wrow[o], m2h, acc[o]);
      acc[10 + o] = fmaf(softplus(w_sigma2[o * DH + h]), msq, acc[10 + o]);
    }
    int idx = 20;
#pragma unroll
    for (int o = 0; o < 10; o++) {
      const float wd = wrow[o] * d2h;
#pragma unroll
      for (int p = o; p < 10; p++) {
        acc[idx] = fmaf(wd, wrow[p], acc[idx]);
        idx++;
      }
    }
  }

  const int lane = t & 63, wv = t >> 6;
#pragma unroll
  for (int j = 0; j < 75; j++) {
    float v = acc[j];
    for (int off = 32; off > 0; off >>= 1) v += __shfl_down(v, off);
    if (lane == 0) red[wv][j] = v;
  }
  __syncthreads();
  if (t < 75) {
    float v = 0.f;
#pragma unroll
    for (int w = 0; w < 8; w++) v += red[w][t];
    fin[t] = v;
  }
  __syncthreads();

  if (t < 10) {
    mu3[t] = fin[t] + b_mu2[t];
    spb2[t] = softplus(b_sigma2[t]);
    // faithful replication of the reshape-trace: tr[b,o] = tr_raw[o2, c]
    const int c0 = b * 10 + t;
    const int o2 = c0 >> 8, cc = c0 & 255;
    float mua = b_mu1[cc], qa = 0.f;
    float mub = b_mu1[256 + cc], qb = 0.f;
#pragma unroll
    for (int g = 0; g < 7; g++) {
      const float4 v = trp[t][g];
      mua += v.x;
      qa += v.y;
      mub += v.z;
      qb += v.w;
    }
    const float d2aa = mua > 0.f ? (qa + softplus(b_sigma1[cc])) : 0.f;
    const float d2bb = mub > 0.f ? (qb + softplus(b_sigma1[256 + cc])) : 0.f;
    trv[t] = softplus(w_sigma2[o2 * DH + 2 * cc]) * d2aa +
             softplus(w_sigma2[o2 * DH + 2 * cc + 1]) * d2bb;
  }
  __syncthreads();

  if (t == 0) {
    float mx = mu3[0];
#pragma unroll
    for (int o = 1; o < 10; o++) mx = fmaxf(mx, mu3[o]);
    float e[10], se = 0.f;
#pragma unroll
    for (int o = 0; o < 10; o++) {
      e[o] = __expf(mu3[o] - mx);
      se += e[o];
    }
    const float inv = 1.f / se;
#pragma unroll
    for (int o = 0; o < 10; o++) pvec[o] = e[o] * inv;
  }
  __syncthreads();

  if (t < 100) {
    const int o = t / 10, p = t % 10;
    const int i0 = o < p ? o : p, j0 = o < p ? p : o;
    const int idx = 10 * i0 - (i0 * (i0 - 1)) / 2 + (j0 - i0);
    float v = fin[20 + idx];  // mid[o][p]
    if (o == p) v += trv[o] + fin[10 + o] + spb2[o];
    sig[o][p] = v;
  }
  __syncthreads();

  if (t < 10) {  // cs[k] = sum_j p[j] * sig[j][k]
    float s = 0.f;
#pragma unroll
    for (int j = 0; j < 10; j++) s = fmaf(pvec[j], sig[j][t], s);
    cs[t] = s;
  }
  __syncthreads();

  if (t < 100) {  // T[i][k] = p[i] * (sig[i][k] - cs[k])
    const int o = t / 10, p = t % 10;
    Tm[o][p] = pvec[o] * (sig[o][p] - cs[p]);
  }
  __syncthreads();

  if (t < 10) {  // rs[i] = sum_k T[i][k] * p[k]
    float s = 0.f;
#pragma unroll
    for (int k = 0; k < 10; k++) s = fmaf(Tm[t][k], pvec[k], s);
    rs[t] = s;
  }
  __syncthreads();

  if (t < 100) {  // Sigma_out[i][l] = p[l] * (T[i][l] - rs[i])
    const int o = t / 10, p = t % 10;
    out_sigma[b * 100 + t] = pvec[p] * (Tm[o][p] - rs[o]);
  }
  if (t < 10) out_p[b * 10 + t] = pvec[t];

  // ---- KL finalize (block 0 only; sync executed uniformly by all) ----
  float klv = (b == 0 && t < 464) ? kl_part[t] : 0.f;
  for (int off = 32; off > 0; off >>= 1) klv += __shfl_down(klv, off);
  if (lane == 0) klred[wv] = klv;
  __syncthreads();
  if (b == 0 && t == 0) {
    float s = 0.f;
#pragma unroll
    for (int w = 0; w < 8; w++) s += klred[w];
    out_kl[0] = 0.5f * (s - 406528.0f);
  }
}

extern "C" void kernel_launch(void* const* d_in, const int* in_sizes, int n_in,
                              void* d_out, int out_size, void* d_ws,
                              size_t ws_size, hipStream_t stream) {
  const float* x = (const float*)d_in[0];
  const float* w_mu1 = (const float*)d_in[1];
  const float* w_sigma1 = (const float*)d_in[2];
  const float* b_mu1 = (const float*)d_in[3];
  const float* b_sigma1 = (const float*)d_in[4];
  const float* w_mu2 = (const float*)d_in[5];
  const float* w_sigma2 = (const float*)d_in[6];
  const float* b_mu2 = (const float*)d_in[7];
  const float* b_sigma2 = (const float*)d_in[8];

  float* out = (float*)d_out;
  float* out_p = out;             // 256*10
  float* out_sigma = out + 2560;  // 256*100
  float* out_kl = out + 28160;    // 1

  float* ws = (float*)d_ws;
  float* mu_part = ws;                            // 28*256*512
  float* q_part = ws + SPLITS * BATCH * DH;       // 28*256*512
  float* kl_part = ws + 2 * SPLITS * BATCH * DH;  // 464

  gemm1_kernel<<<dim3(8, 4, SPLITS), 256, 0, stream>>>(
      x, w_mu1, w_sigma1, w_mu2, w_sigma2, mu_part, q_part, kl_part);
  layer2_kernel<<<256, 512, 0, stream>>>(mu_part, q_part, b_mu1, b_sigma1,
                                         w_mu2, w_sigma2, b_mu2, b_sigma2,
                                         kl_part, out_p, out_sigma, out_kl);
}